// Round 17
// baseline (328.296 us; speedup 1.0000x reference)
//
#include <hip/hip_runtime.h>
#include <stdint.h>
#include <math.h>

constexpr int NPG = 32768;
constexpr int NGRAPH = 128;
constexpr int L1 = 5, L2 = 64, L3 = 32, L4 = 8;
constexpr int K1 = 328, K2 = 33, K3 = 4;
constexpr int SEGS = 16;            // score blocks per graph
constexpr int CAP  = 64;            // per-segment candidate capacity (E=26, sd=5)
constexpr int SLOTS = SEGS * CAP;   // 1024 candidate slots per graph

__device__ __forceinline__ uint32_t mono(float f) {
  uint32_t u = __float_as_uint(f);
  return (u & 0x80000000u) ? ~u : (u | 0x80000000u);
}
__device__ __forceinline__ float imono(uint32_t k) {
  uint32_t u = (k & 0x80000000u) ? (k ^ 0x80000000u) : ~k;
  return __uint_as_float(u);
}
// robust fast tanh: 1 - 2/(e^{2x}+1); passed absmax 0.0 in r10-r16
__device__ __forceinline__ float fast_tanh(float x) {
  float e = __expf(2.0f * x);
  return 1.0f - 2.0f / (e + 1.0f);
}

// ============ fused kernel: score + compaction + RNN/s2 precompute; ============
// ============ per-graph LAST block (atomic counter) runs the tail MLP ==========
// 2048 blocks x 256 threads, ~48 KB LDS -> 3 blocks/CU.
__global__ __launch_bounds__(256) void fused_kernel(
    const float* __restrict__ x, const float* __restrict__ w1,
    const float* __restrict__ W_ih, const float* __restrict__ b_ih,
    const float* __restrict__ b_hh, const float* __restrict__ w2,
    const float* __restrict__ W2, const float* __restrict__ b2,
    const float* __restrict__ w3, const float* __restrict__ W3,
    const float* __restrict__ b3,
    int* __restrict__ cnts, unsigned long long* __restrict__ cand,
    float* __restrict__ s2g, float* __restrict__ hG,
    int* __restrict__ done, float* __restrict__ out) {
  // arena: score {sb[10240]} ; tail {comp 0..2048, sorted 2048..3072,
  //  slotarr 3072..4096, slotof 4096..4480, x2f 4480..6724, yf 6724..7813,
  //  sW2t 7816..9896, sb2t 9896, sw3t 9928, sW3t 9960..10216, sb3t 10216..10224}
  __shared__ __align__(16) float arena[11264];      // 44 KB
  __shared__ unsigned long long cb[CAP];            // score cands / fallback top-33
  __shared__ float xs[CAP * L1];
  __shared__ float sWih[L2 * L1];
  __shared__ float sbih[L2];
  __shared__ float sw2[L2];
  __shared__ int soff[SEGS + 1];
  __shared__ int wred[4];
  __shared__ int s_n, s_last, s_fb, s_ctot, s_lo, s_hi, s_done, s_cnt;
  __shared__ uint32_t s_T;
  __shared__ float s_tf, s_inv1, s_inv2, s_inv3;

  const int tid = threadIdx.x;
  const int wid = tid >> 6, lane = tid & 63;
  const int g = blockIdx.x >> 4;
  const int bg = blockIdx.x & 15;
  const float* xg = x + (size_t)g * NPG * L1;

  if (tid == 0) {
    s_n = 0;
    float s = 0.f;
    for (int k = 0; k < L1; ++k) s += w1[k] * w1[k];
    float nw = sqrtf(s);
    s_tf = 2.2315f * nw;   // analytic rank-328/32768 prior (E[count]=420)
    s_inv1 = 1.f / nw;
  }
  for (int i = tid; i < L2 * L1; i += 256) sWih[i] = W_ih[i];
  for (int i = tid; i < L2; i += 256) { sbih[i] = b_ih[i] + b_hh[i]; sw2[i] = w2[i]; }
  const float w10 = w1[0], w11 = w1[1], w12 = w1[2], w13 = w1[3], w14 = w1[4];

  // ---- phase A: score 2048 nodes (LDS-staged), compact vs analytic T ----
  {
    float* sb = arena;
    const float4* src = (const float4*)(x + ((size_t)g * NPG + bg * 2048) * L1);
#pragma unroll
    for (int k = 0; k < 10; ++k)
      ((float4*)sb)[tid + 256 * k] = src[tid + 256 * k];
    __syncthreads();
    const float tf = s_tf;
#pragma unroll
    for (int p = 0; p < 4; ++p) {
      const int np = tid + 256 * p;                 // node pair
      const float* r = sb + np * 10;
      float d0 = r[0]*w10 + r[1]*w11 + r[2]*w12 + r[3]*w13 + r[4]*w14;
      float d1 = r[5]*w10 + r[6]*w11 + r[7]*w12 + r[8]*w13 + r[9]*w14;
      const int i0 = bg * 2048 + 2 * np;
      if (d0 >= tf) {
        int pos = atomicAdd(&s_n, 1);
        if (pos < CAP)
          cb[pos] = ((unsigned long long)mono(d0) << 16) | (unsigned)(65535 - i0);
      }
      if (d1 >= tf) {
        int pos = atomicAdd(&s_n, 1);
        if (pos < CAP)
          cb[pos] = ((unsigned long long)mono(d1) << 16) | (unsigned)(65535 - (i0 + 1));
      }
    }
    __syncthreads();
    const int n = s_n;
    const int nn = n < CAP ? n : CAP;
    if (tid == 0) cnts[g * SEGS + bg] = n;
    if (tid < CAP && tid < n)
      cand[((size_t)g * SEGS + bg) * CAP + tid] = cb[tid];
    // rank-independent xsel rows (from LDS-resident sb)
    for (int p = tid; p < nn * L1; p += 256) {
      int ci = p / L1, k = p - ci * L1;
      unsigned long long c = cb[ci];
      int i = 65535 - (int)(c & 0xFFFFu);
      int local = i - bg * 2048;
      float sc = fast_tanh(imono((uint32_t)(c >> 16)) * s_inv1);
      xs[p] = sb[local * L1 + k] * sc;
    }
    __syncthreads();
    // RNN row + s2 dot (wave-uniform ci, o=lane) -> hG, s2g
    for (int p = tid; p < nn * 64; p += 256) {
      int ci = p >> 6, o = p & 63;
      const float* xr = xs + ci * L1;
      const float* wr = sWih + o * L1;
      float acc = sbih[o];
#pragma unroll
      for (int k = 0; k < L1; ++k) acc += xr[k] * wr[k];
      float h = fast_tanh(acc);
      const int slot = bg * CAP + ci;
      hG[((size_t)g * SLOTS + slot) * 64 + o] = h;
      float term = h * sw2[o];
      for (int d = 1; d < 64; d <<= 1) term += __shfl_xor(term, d);
      if (o == 0) s2g[(size_t)g * SLOTS + slot] = term;
    }
  }

  // ---- phase B: release + last-block election ----
  __threadfence();                  // each thread releases its own stores
  __syncthreads();
  if (tid == 0) s_last = (atomicAdd(&done[g], 1) == SEGS - 1) ? 1 : 0;
  __syncthreads();
  if (!s_last) return;
  __threadfence();                  // acquire: see all 16 segments' data

  // ---- phase C: tail MLP for graph g (256 threads) ----
  unsigned long long* comp = (unsigned long long*)arena;        // 1024
  unsigned long long* sorted = (unsigned long long*)(arena + 2048); // 512
  int* slotarr = (int*)(arena + 3072);                          // 1024
  int* slotof  = (int*)(arena + 4096);                          // 384
  float* x2f = arena + 4480;                                    // [33][68]
  float* yf  = arena + 6724;                                    // [33][33]
  float* sW2t = arena + 7816;                                   // [32][65]
  float* sb2t = arena + 9896;
  float* sw3t = arena + 9928;
  float* sW3t = arena + 9960;
  float* sb3t = arena + 10216;

  if (tid < SEGS) soff[tid] = cnts[g * SEGS + tid];
  for (int i = tid; i < L3 * L2; i += 256) sW2t[(i >> 6) * 65 + (i & 63)] = W2[i];
  if (tid < L3) { sb2t[tid] = b2[tid]; sw3t[tid] = w3[tid]; }
  if (tid < L4 * L3) sW3t[tid] = W3[tid];
  if (tid < L4) sb3t[tid] = b3[tid];
  if (tid < 64) {
    float b = sw2[tid];
    float c = (tid < L3) ? w3[tid] : 0.f;
    b *= b; c *= c;
    for (int d = 1; d < 64; d <<= 1) { b += __shfl_xor(b, d); c += __shfl_xor(c, d); }
    if (tid == 0) { s_inv2 = 1.f / sqrtf(b); s_inv3 = 1.f / sqrtf(c); }
  }
  __syncthreads();
  if (tid == 0) {   // serial scan + exactness gate
    int off = 0, fb = 0;
    for (int s2 = 0; s2 < SEGS; ++s2) {
      int c = soff[s2];
      if (c > CAP) fb = 1;
      soff[s2] = off;
      off += c;
    }
    soff[SEGS] = off;
    if (off < K1 || off > 1024) fb = 1;   // prior missed (P~1e-13)
    s_fb = fb; s_ctot = off;
  }
  __syncthreads();
  const float inv2 = s_inv2, inv3 = s_inv3;

  if (!s_fb) {
    // gather composites + slots (4 waves x 4 segments)
    for (int seg = wid; seg < SEGS; seg += 4) {
      const int o = soff[seg], c = soff[seg + 1] - o;
      if (lane < c) {
        comp[o + lane] = cand[((size_t)g * SEGS + seg) * CAP + lane];
        slotarr[o + lane] = seg * CAP + lane;
      }
    }
    const int ctot = s_ctot;
    const int nrk = (ctot + 7) & ~7;      // typ. ~424
    for (int p = tid; p < nrk; p += 256)
      if (p >= ctot) comp[p] = 0ULL;
    __syncthreads();
    for (int p = tid; p < nrk; p += 256) {   // broadcast counting-rank -> slot map
      unsigned long long c = comp[p];
      int r = 0;
      for (int i = 0; i < nrk; i += 8) {
        ulonglong2 v0 = *(const ulonglong2*)&comp[i];
        ulonglong2 v1 = *(const ulonglong2*)&comp[i + 2];
        ulonglong2 v2 = *(const ulonglong2*)&comp[i + 4];
        ulonglong2 v3 = *(const ulonglong2*)&comp[i + 6];
        r += (v0.x > c) + (v0.y > c) + (v1.x > c) + (v1.y > c) +
             (v2.x > c) + (v2.y > c) + (v3.x > c) + (v3.y > c);
      }
      if (r < K1) slotof[r] = slotarr[p];
    }
    __syncthreads();
    // pool2 keys from precomputed s2 (tie-break by pool1 rank j)
    for (int j = tid; j < 384; j += 256) {
      unsigned long long c = 0ULL;
      if (j < K1) {
        float s2 = s2g[(size_t)g * SLOTS + slotof[j]];
        c = ((unsigned long long)mono(s2) << 16) | (unsigned)(65535 - j);
      }
      comp[j] = c;
    }
    __syncthreads();
    for (int p = tid; p < 384; p += 256) {
      unsigned long long c = comp[p];
      int r = 0;
      for (int i = 0; i < 384; i += 8) {
        ulonglong2 v0 = *(const ulonglong2*)&comp[i];
        ulonglong2 v1 = *(const ulonglong2*)&comp[i + 2];
        ulonglong2 v2 = *(const ulonglong2*)&comp[i + 4];
        ulonglong2 v3 = *(const ulonglong2*)&comp[i + 6];
        r += (v0.x > c) + (v0.y > c) + (v1.x > c) + (v1.y > c) +
             (v2.x > c) + (v2.y > c) + (v3.x > c) + (v3.y > c);
      }
      sorted[r] = c;
    }
    __syncthreads();
    // x2 from precomputed h rows
    for (int p = tid; p < K2 * L2; p += 256) {
      int j = p >> 6, k = p & 63;
      unsigned long long c = sorted[j];
      int jp = 65535 - (int)(c & 0xFFFFu);   // pool1 rank
      float sc = fast_tanh(imono((uint32_t)(c >> 16)) * inv2);
      x2f[j * 68 + k] = hG[((size_t)g * SLOTS + slotof[jp]) * 64 + k] * sc;
    }
    __syncthreads();
  } else {
    // ---- exact fallback (never expected): recompute without hbuf ----
    float* sWihF = (float*)slotarr;       // 320 + 64 (overlays slotarr)
    float* sbihF = sWihF + 320;
    float* s2F   = (float*)slotof;        // 328 (overlays slotof)
    for (int i = tid; i < L2 * L1; i += 256) sWihF[i] = W_ih[i];
    if (tid < L2) sbihF[tid] = b_ih[tid] + b_hh[tid];
    if (tid == 0) { s_lo = 0; s_hi = -1; s_done = 0; s_cnt = 0; }
    __syncthreads();
    for (int it = 0; it < 36; ++it) {     // binary search on mono32
      if (s_done) break;
      const uint32_t lo = (uint32_t)s_lo, hi = (uint32_t)s_hi;
      const uint32_t q = (uint32_t)(((unsigned long long)lo + (unsigned long long)hi) >> 1);
      int cc = 0;
      for (int m = 0; m < 128; ++m) {
        const int i = m * 256 + tid;
        const float* r = xg + (size_t)i * L1;
        float dv = r[0]*w10 + r[1]*w11 + r[2]*w12 + r[3]*w13 + r[4]*w14;
        cc += (mono(dv) >= q);
      }
      for (int d = 1; d < 64; d <<= 1) cc += __shfl_xor(cc, d);
      if (lane == 0) wred[wid] = cc;
      __syncthreads();
      if (tid == 0) {
        int tot = wred[0] + wred[1] + wred[2] + wred[3];
        if (tot >= K1 && tot <= 1024) { s_T = q; s_done = 1; }
        else if ((uint32_t)s_hi - (uint32_t)s_lo <= 1u) { s_T = (uint32_t)s_lo; s_done = 1; }
        else if (tot > 1024) { s_lo = (int)q; }
        else                 { s_hi = (int)q; }
      }
      __syncthreads();
    }
    const uint32_t T = s_T;
    for (int m = 0; m < 128; ++m) {
      const int i = m * 256 + tid;
      const float* r = xg + (size_t)i * L1;
      float dv = r[0]*w10 + r[1]*w11 + r[2]*w12 + r[3]*w13 + r[4]*w14;
      if (mono(dv) >= T) {
        int p = atomicAdd(&s_cnt, 1);
        if (p < 1024)
          comp[p] = ((unsigned long long)mono(dv) << 16) | (unsigned)(65535 - i);
      }
    }
    __syncthreads();
    int cnt = s_cnt; if (cnt > 1024) cnt = 1024;
    int nrk = (cnt + 7) & ~7; if (nrk < 8) nrk = 8;
    for (int p = tid; p < nrk; p += 256)
      if (p >= cnt) comp[p] = 0ULL;
    __syncthreads();
    for (int p = tid; p < nrk; p += 256) {
      unsigned long long c = comp[p];
      int r = 0;
      for (int i = 0; i < nrk; i += 8) {
        ulonglong2 v0 = *(const ulonglong2*)&comp[i];
        ulonglong2 v1 = *(const ulonglong2*)&comp[i + 2];
        ulonglong2 v2 = *(const ulonglong2*)&comp[i + 4];
        ulonglong2 v3 = *(const ulonglong2*)&comp[i + 6];
        r += (v0.x > c) + (v0.y > c) + (v1.x > c) + (v1.y > c) +
             (v2.x > c) + (v2.y > c) + (v3.x > c) + (v3.y > c);
      }
      if (r < K1) sorted[r] = c;
    }
    __syncthreads();
    // s2 per pool1 rank (wave per row)
    for (int j = wid; j < K1; j += 4) {
      unsigned long long c = sorted[j];
      int i = 65535 - (int)(c & 0xFFFFu);
      float sc = fast_tanh(imono((uint32_t)(c >> 16)) * s_inv1);
      const float* r = xg + (size_t)i * L1;
      float xr[5];
#pragma unroll
      for (int k = 0; k < L1; ++k) xr[k] = r[k] * sc;
      const int o = lane;
      const float* wr = sWihF + o * L1;
      float acc = sbihF[o];
#pragma unroll
      for (int k = 0; k < L1; ++k) acc += xr[k] * wr[k];
      float h = fast_tanh(acc);
      float term = h * sw2[o];
      for (int d = 1; d < 64; d <<= 1) term += __shfl_xor(term, d);
      if (o == 0) s2F[j] = term;
    }
    __syncthreads();
    for (int j = tid; j < 384; j += 256)
      comp[j] = (j < K1)
          ? (((unsigned long long)mono(s2F[j]) << 16) | (unsigned)(65535 - j)) : 0ULL;
    __syncthreads();
    for (int p = tid; p < 384; p += 256) {
      unsigned long long c = comp[p];
      int r = 0;
      for (int i = 0; i < 384; i += 8) {
        ulonglong2 v0 = *(const ulonglong2*)&comp[i];
        ulonglong2 v1 = *(const ulonglong2*)&comp[i + 2];
        ulonglong2 v2 = *(const ulonglong2*)&comp[i + 4];
        ulonglong2 v3 = *(const ulonglong2*)&comp[i + 6];
        r += (v0.x > c) + (v0.y > c) + (v1.x > c) + (v1.y > c) +
             (v2.x > c) + (v2.y > c) + (v3.x > c) + (v3.y > c);
      }
      if (r < CAP) cb[r] = c;   // top-33 pool2 composites
    }
    __syncthreads();
    for (int j = wid; j < K2; j += 4) {     // x2 rows: recompute h
      unsigned long long c2 = cb[j];
      int jp = 65535 - (int)(c2 & 0xFFFFu);
      float sc2 = fast_tanh(imono((uint32_t)(c2 >> 16)) * inv2);
      unsigned long long c1 = sorted[jp];
      int i = 65535 - (int)(c1 & 0xFFFFu);
      float sc1 = fast_tanh(imono((uint32_t)(c1 >> 16)) * s_inv1);
      const float* r = xg + (size_t)i * L1;
      float xr[5];
#pragma unroll
      for (int k = 0; k < L1; ++k) xr[k] = r[k] * sc1;
      const int o = lane;
      const float* wr = sWihF + o * L1;
      float acc = sbihF[o];
#pragma unroll
      for (int k = 0; k < L1; ++k) acc += xr[k] * wr[k];
      x2f[j * 68 + o] = fast_tanh(acc) * sc2;
    }
    __syncthreads();
  }

  // ---- common tail: H, pool3, J ----
  for (int p = tid; p < K2 * L3; p += 256) {
    int j = p >> 5, o = p & 31;
    const float4* xr4 = (const float4*)(x2f + j * 68);
    const float* wr = sW2t + o * 65;
    float acc = sb2t[o];
#pragma unroll
    for (int m = 0; m < 16; ++m) {
      float4 v = xr4[m];
      acc += v.x * wr[4 * m];     acc += v.y * wr[4 * m + 1];
      acc += v.z * wr[4 * m + 2]; acc += v.w * wr[4 * m + 3];
    }
    yf[j * 33 + o] = fmaxf(acc, 0.f);
  }
  __syncthreads();
  if (tid < 64) {
    unsigned long long c = 0ULL;
    if (tid < K2) {
      const float* yr = yf + tid * 33;
      float acc = 0.f;
      for (int k = 0; k < L3; ++k) acc += yr[k] * sw3t[k];
      c = ((unsigned long long)mono(acc) << 16) | (unsigned)(65535 - tid);
    }
    comp[tid] = c;
  }
  __syncthreads();
  if (tid < 64) {
    unsigned long long c = comp[tid];
    int r = 0;
    for (int i = 0; i < 64; i += 8) {
      ulonglong2 v0 = *(const ulonglong2*)&comp[i];
      ulonglong2 v1 = *(const ulonglong2*)&comp[i + 2];
      ulonglong2 v2 = *(const ulonglong2*)&comp[i + 4];
      ulonglong2 v3 = *(const ulonglong2*)&comp[i + 6];
      r += (v0.x > c) + (v0.y > c) + (v1.x > c) + (v1.y > c) +
           (v2.x > c) + (v2.y > c) + (v3.x > c) + (v3.y > c);
    }
    sorted[r] = c;
  }
  __syncthreads();
  if (tid < K3 * L4) {
    int t = tid >> 3, o = tid & 7;
    unsigned long long c = sorted[t];
    int row = 65535 - (int)(c & 0xFFFFu);
    float sc = fast_tanh(imono((uint32_t)(c >> 16)) * inv3);
    const float* yr = yf + row * 33;
    const float* wr = sW3t + o * L3;
    float acc = sb3t[o];
    for (int k = 0; k < L3; ++k) acc += yr[k] * sc * wr[k];
    out[((size_t)g * K3 + t) * L4 + o] = acc;
  }
}

// ============ safety net (ws too small; never expected): standalone exact ============
__global__ __launch_bounds__(1024, 1) void exact_kernel(
    const float* __restrict__ x,
    const float* __restrict__ w1, const float* __restrict__ W_ih,
    const float* __restrict__ b_ih, const float* __restrict__ b_hh,
    const float* __restrict__ w2, const float* __restrict__ W2,
    const float* __restrict__ b2, const float* __restrict__ w3,
    const float* __restrict__ W3, const float* __restrict__ b3,
    float* __restrict__ out) {
  __shared__ __align__(16) float hbuf[K1 * 65 + K2 * 68 + K2 * 33];
  __shared__ __align__(16) unsigned long long comp[1024];
  __shared__ __align__(16) unsigned long long sorted[512];
  __shared__ __align__(16) float fa[5672];
  __shared__ int wred[16];
  __shared__ int s_lo, s_hi, s_done, s_cnt;
  __shared__ uint32_t s_T;
  __shared__ float s_inv[3];

  float* xsel  = fa;
  float* sWihP = fa + 2624;
  float* sbih  = fa + 3136;
  float* sW2   = fa + 3200;
  float* sb2   = fa + 5280;
  float* sw2v  = fa + 5312;
  float* sw3v  = fa + 5376;
  float* sW3   = fa + 5408;
  float* sb3   = fa + 5664;

  const int tid = threadIdx.x;
  const int wid = tid >> 6;
  const int g = blockIdx.x;
  const float* xg = x + (size_t)g * NPG * L1;
  const float w10 = w1[0], w11 = w1[1], w12 = w1[2], w13 = w1[3], w14 = w1[4];

  for (int i = tid; i < 512; i += 1024) {
    int o = i >> 3, k = i & 7;
    sWihP[i] = (k < L1) ? W_ih[o * L1 + k] : 0.f;
  }
  for (int i = tid; i < L2; i += 1024) { sbih[i] = b_ih[i] + b_hh[i]; sw2v[i] = w2[i]; }
  for (int i = tid; i < L3 * L2; i += 1024) sW2[(i >> 6) * 65 + (i & 63)] = W2[i];
  for (int i = tid; i < L3; i += 1024) { sb2[i] = b2[i]; sw3v[i] = w3[i]; }
  for (int i = tid; i < L4 * L3; i += 1024) sW3[i] = W3[i];
  for (int i = tid; i < L4; i += 1024) sb3[i] = b3[i];
  if (tid < 64) {
    float a = (tid < L1) ? w1[tid] : 0.f;
    float b = w2[tid];
    float c = (tid < L3) ? w3[tid] : 0.f;
    a *= a; b *= b; c *= c;
    for (int d = 1; d < 64; d <<= 1) {
      a += __shfl_xor(a, d); b += __shfl_xor(b, d); c += __shfl_xor(c, d);
    }
    if (tid == 0) {
      s_inv[0] = 1.f / sqrtf(a); s_inv[1] = 1.f / sqrtf(b); s_inv[2] = 1.f / sqrtf(c);
      s_cnt = 0; s_done = 0; s_lo = 0; s_hi = -1;
    }
  }
  __syncthreads();
  for (int it = 0; it < 36; ++it) {
    if (s_done) break;
    const uint32_t lo = (uint32_t)s_lo, hi = (uint32_t)s_hi;
    const uint32_t q = (uint32_t)(((unsigned long long)lo + (unsigned long long)hi) >> 1);
    int cc = 0;
    for (int m = 0; m < 32; ++m) {
      const int i = m * 1024 + tid;
      const float* r = xg + (size_t)i * L1;
      float dv = r[0]*w10 + r[1]*w11 + r[2]*w12 + r[3]*w13 + r[4]*w14;
      cc += (mono(dv) >= q);
    }
    for (int d = 1; d < 64; d <<= 1) cc += __shfl_xor(cc, d);
    if ((tid & 63) == 0) wred[wid] = cc;
    __syncthreads();
    if (tid == 0) {
      int tot = 0;
      for (int w = 0; w < 16; ++w) tot += wred[w];
      if (tot >= K1 && tot <= 1024) { s_T = q; s_done = 1; }
      else if ((uint32_t)s_hi - (uint32_t)s_lo <= 1u) { s_T = (uint32_t)s_lo; s_done = 1; }
      else if (tot > 1024) { s_lo = (int)q; }
      else                 { s_hi = (int)q; }
    }
    __syncthreads();
  }
  const uint32_t T = s_T;
  for (int m = 0; m < 32; ++m) {
    const int i = m * 1024 + tid;
    const float* r = xg + (size_t)i * L1;
    float dv = r[0]*w10 + r[1]*w11 + r[2]*w12 + r[3]*w13 + r[4]*w14;
    if (mono(dv) >= T) {
      int p = atomicAdd(&s_cnt, 1);
      if (p < 1024)
        comp[p] = ((unsigned long long)mono(dv) << 16) | (unsigned)(65535 - i);
    }
  }
  __syncthreads();
  int cnt = s_cnt; if (cnt > 1024) cnt = 1024;
  int nrk = (cnt + 7) & ~7; if (nrk < 8) nrk = 8;
  if (tid >= cnt && tid < nrk) comp[tid] = 0ULL;
  __syncthreads();
  if (tid < nrk) {
    unsigned long long c = comp[tid];
    int r = 0;
    for (int i = 0; i < nrk; i += 8) {
      ulonglong2 v0 = *(const ulonglong2*)&comp[i];
      ulonglong2 v1 = *(const ulonglong2*)&comp[i + 2];
      ulonglong2 v2 = *(const ulonglong2*)&comp[i + 4];
      ulonglong2 v3 = *(const ulonglong2*)&comp[i + 6];
      r += (v0.x > c) + (v0.y > c) + (v1.x > c) + (v1.y > c) +
           (v2.x > c) + (v2.y > c) + (v3.x > c) + (v3.y > c);
    }
    if (r < K1) sorted[r] = c;
  }
  __syncthreads();
  const float inv1 = s_inv[0], inv2 = s_inv[1], inv3 = s_inv[2];
  for (int p = tid; p < K1 * 8; p += 1024) {
    int j = p >> 3, k = p & 7;
    unsigned long long c = sorted[j];
    int idx = 65535 - (int)(c & 0xFFFFu);
    float sc = fast_tanh(imono((uint32_t)(c >> 16)) * inv1);
    xsel[p] = (k < L1) ? xg[(size_t)idx * L1 + k] * sc : 0.f;
  }
  __syncthreads();
  {
    const int o = tid & 63;
    float wreg[8];
#pragma unroll
    for (int k = 0; k < 8; ++k) wreg[k] = sWihP[o * 8 + k];
    const float bias = sbih[o];
    for (int p = tid; p < K1 * L2; p += 1024) {
      int row = p >> 6;
      float4 xa = *(const float4*)&xsel[row * 8];
      float4 xb = *(const float4*)&xsel[row * 8 + 4];
      float acc = bias;
      acc += xa.x * wreg[0]; acc += xa.y * wreg[1]; acc += xa.z * wreg[2];
      acc += xa.w * wreg[3]; acc += xb.x * wreg[4]; acc += xb.y * wreg[5];
      acc += xb.z * wreg[6]; acc += xb.w * wreg[7];
      hbuf[row * 65 + o] = fast_tanh(acc);
    }
  }
  __syncthreads();
  for (int j = tid; j < 384; j += 1024) {
    unsigned long long c = 0ULL;
    if (j < K1) {
      const float* hr = hbuf + j * 65;
      float acc = 0.f;
      for (int k = 0; k < L2; ++k) acc += hr[k] * sw2v[k];
      c = ((unsigned long long)mono(acc) << 16) | (unsigned)(65535 - j);
    }
    comp[j] = c;
  }
  __syncthreads();
  if (tid < 384) {
    unsigned long long c = comp[tid];
    int r = 0;
    for (int i = 0; i < 384; i += 8) {
      ulonglong2 v0 = *(const ulonglong2*)&comp[i];
      ulonglong2 v1 = *(const ulonglong2*)&comp[i + 2];
      ulonglong2 v2 = *(const ulonglong2*)&comp[i + 4];
      ulonglong2 v3 = *(const ulonglong2*)&comp[i + 6];
      r += (v0.x > c) + (v0.y > c) + (v1.x > c) + (v1.y > c) +
           (v2.x > c) + (v2.y > c) + (v3.x > c) + (v3.y > c);
    }
    sorted[r] = c;
  }
  __syncthreads();
  float* x2f = hbuf + K1 * 65;
  float* yf  = x2f + K2 * 68;
  for (int p = tid; p < K2 * L2; p += 1024) {
    int j = p >> 6, k = p & 63;
    unsigned long long c = sorted[j];
    int row = 65535 - (int)(c & 0xFFFFu);
    float sc = fast_tanh(imono((uint32_t)(c >> 16)) * inv2);
    x2f[j * 68 + k] = hbuf[row * 65 + k] * sc;
  }
  __syncthreads();
  for (int p = tid; p < K2 * L3; p += 1024) {
    int j = p >> 5, o = p & 31;
    const float4* xr4 = (const float4*)(x2f + j * 68);
    const float* wr = sW2 + o * 65;
    float acc = sb2[o];
#pragma unroll
    for (int m = 0; m < 16; ++m) {
      float4 v = xr4[m];
      acc += v.x * wr[4 * m];     acc += v.y * wr[4 * m + 1];
      acc += v.z * wr[4 * m + 2]; acc += v.w * wr[4 * m + 3];
    }
    yf[j * 33 + o] = fmaxf(acc, 0.f);
  }
  __syncthreads();
  for (int j = tid; j < 64; j += 1024) {
    unsigned long long c = 0ULL;
    if (j < K2) {
      const float* yr = yf + j * 33;
      float acc = 0.f;
      for (int k = 0; k < L3; ++k) acc += yr[k] * sw3v[k];
      c = ((unsigned long long)mono(acc) << 16) | (unsigned)(65535 - j);
    }
    comp[j] = c;
  }
  __syncthreads();
  if (tid < 64) {
    unsigned long long c = comp[tid];
    int r = 0;
    for (int i = 0; i < 64; i += 8) {
      ulonglong2 v0 = *(const ulonglong2*)&comp[i];
      ulonglong2 v1 = *(const ulonglong2*)&comp[i + 2];
      ulonglong2 v2 = *(const ulonglong2*)&comp[i + 4];
      ulonglong2 v3 = *(const ulonglong2*)&comp[i + 6];
      r += (v0.x > c) + (v0.y > c) + (v1.x > c) + (v1.y > c) +
           (v2.x > c) + (v2.y > c) + (v3.x > c) + (v3.y > c);
    }
    sorted[r] = c;
  }
  __syncthreads();
  for (int p = tid; p < K3 * L4; p += 1024) {
    int t = p >> 3, o = p & 7;
    unsigned long long c = sorted[t];
    int row = 65535 - (int)(c & 0xFFFFu);
    float sc = fast_tanh(imono((uint32_t)(c >> 16)) * inv3);
    const float* yr = yf + row * 33;
    const float* wr = sW3 + o * L3;
    float acc = sb3[o];
    for (int k = 0; k < L3; ++k) acc += yr[k] * sc * wr[k];
    out[((size_t)g * K3 + t) * L4 + o] = acc;
  }
}

extern "C" void kernel_launch(void* const* d_in, const int* in_sizes, int n_in,
                              void* d_out, int out_size, void* d_ws, size_t ws_size,
                              hipStream_t stream) {
  const float* x    = (const float*)d_in[0];
  // d_in[1] = edge_index (unused), d_in[2] = batch (unused: static contiguous grouping)
  const float* w1   = (const float*)d_in[3];
  const float* W_ih = (const float*)d_in[4];
  const float* b_ih = (const float*)d_in[5];
  const float* b_hh = (const float*)d_in[6];
  const float* w2   = (const float*)d_in[7];
  const float* W2   = (const float*)d_in[8];
  const float* b2   = (const float*)d_in[9];
  const float* w3   = (const float*)d_in[10];
  const float* W3   = (const float*)d_in[11];
  const float* b3   = (const float*)d_in[12];
  float* out = (float*)d_out;

  // workspace layout: [done 512B pad->4KB][cnts 8KB][cand 1MB][s2 512KB][hG 33.6MB]
  const size_t done_b = 4096;
  const size_t cnts_b = (size_t)NGRAPH * SEGS * sizeof(int);
  const size_t cand_b = (size_t)NGRAPH * SLOTS * sizeof(unsigned long long);
  const size_t s2_b   = (size_t)NGRAPH * SLOTS * sizeof(float);
  const size_t h_b    = (size_t)NGRAPH * SLOTS * 64 * sizeof(float);
  const size_t need   = done_b + cnts_b + cand_b + s2_b + h_b;   // ~35.2 MB

  if (ws_size >= need) {
    int* done = (int*)d_ws;
    int* cnts = (int*)((char*)d_ws + done_b);
    unsigned long long* cand = (unsigned long long*)((char*)d_ws + done_b + cnts_b);
    float* s2g = (float*)((char*)d_ws + done_b + cnts_b + cand_b);
    float* hG  = (float*)((char*)d_ws + done_b + cnts_b + cand_b + s2_b);
    hipMemsetAsync(done, 0, NGRAPH * sizeof(int), stream);
    fused_kernel<<<dim3(NGRAPH * SEGS), dim3(256), 0, stream>>>(
        x, w1, W_ih, b_ih, b_hh, w2, W2, b2, w3, W3, b3,
        cnts, cand, s2g, hG, done, out);
  } else {
    exact_kernel<<<dim3(NGRAPH), dim3(1024), 0, stream>>>(
        x, w1, W_ih, b_ih, b_hh, w2, W2, b2, w3, W3, b3, out);
  }
}

// Round 18
// 44.947 us; speedup vs baseline: 7.3041x; 7.3041x over previous
//
#include <hip/hip_runtime.h>
#include <stdint.h>
#include <math.h>

constexpr int NPG = 32768;
constexpr int NGRAPH = 128;
constexpr int L1 = 5, L2 = 64, L3 = 32, L4 = 8;
constexpr int K1 = 328, K2 = 33, K3 = 4;
constexpr int SEGS = 16;     // score blocks per graph
constexpr int CAP  = 64;     // per-segment candidate capacity (E=26, sd=5)

__device__ __forceinline__ uint32_t mono(float f) {
  uint32_t u = __float_as_uint(f);
  return (u & 0x80000000u) ? ~u : (u | 0x80000000u);
}
__device__ __forceinline__ float imono(uint32_t k) {
  uint32_t u = (k & 0x80000000u) ? (k ^ 0x80000000u) : ~k;
  return __uint_as_float(u);
}
// robust fast tanh: 1 - 2/(e^{2x}+1); passed absmax 0.0 in r10-r17
__device__ __forceinline__ float fast_tanh(float x) {
  float e = __expf(2.0f * x);
  return 1.0f - 2.0f / (e + 1.0f);
}

// ---- kernel 1: score stream + analytic-threshold compaction (proven 44.9us) ----
// 2048 blocks x 256. T = 2.2315*||w1|| identical across blocks (same serial
// computation on same w1). Writes per-segment count + <=CAP full-precision
// composites ((mono32(d)<<16)|(65535-i)). No atomics across blocks; nothing
// to zero (counts written unconditionally every call).
__global__ __launch_bounds__(256) void score_kernel(
    const float* __restrict__ x, const float* __restrict__ w1,
    int* __restrict__ cnts, unsigned long long* __restrict__ cand) {
  __shared__ __align__(16) float sb[2048 * L1];   // 40 KB
  __shared__ unsigned long long cb[CAP];
  __shared__ int s_n;
  __shared__ float s_tf;
  const int tid = threadIdx.x;
  const int g = blockIdx.x >> 4;
  const int bg = blockIdx.x & 15;
  if (tid == 0) {
    s_n = 0;
    float s = 0.f;
    for (int k = 0; k < L1; ++k) s += w1[k] * w1[k];
    s_tf = 2.2315f * sqrtf(s);   // analytic rank-328/32768 prior (E[count]=420)
  }
  const float w10 = w1[0], w11 = w1[1], w12 = w1[2], w13 = w1[3], w14 = w1[4];
  const float4* src = (const float4*)(x + ((size_t)g * NPG + bg * 2048) * L1);
#pragma unroll
  for (int k = 0; k < 10; ++k)
    ((float4*)sb)[tid + 256 * k] = src[tid + 256 * k];
  __syncthreads();
  const float tf = s_tf;
#pragma unroll
  for (int p = 0; p < 4; ++p) {
    const int np = tid + 256 * p;                 // node pair
    const float* r = sb + np * 10;
    float d0 = r[0]*w10 + r[1]*w11 + r[2]*w12 + r[3]*w13 + r[4]*w14;
    float d1 = r[5]*w10 + r[6]*w11 + r[7]*w12 + r[8]*w13 + r[9]*w14;
    const int i0 = bg * 2048 + 2 * np;            // node index within graph
    if (d0 >= tf) {
      int pos = atomicAdd(&s_n, 1);
      if (pos < CAP)
        cb[pos] = ((unsigned long long)mono(d0) << 16) | (unsigned)(65535 - i0);
    }
    if (d1 >= tf) {
      int pos = atomicAdd(&s_n, 1);
      if (pos < CAP)
        cb[pos] = ((unsigned long long)mono(d1) << 16) | (unsigned)(65535 - (i0 + 1));
    }
  }
  __syncthreads();
  const int n = s_n;
  if (tid == 0) cnts[g * SEGS + bg] = n;          // raw count (selmlp gates on >CAP)
  if (tid < CAP && tid < n)
    cand[((size_t)g * SEGS + bg) * CAP + tid] = cb[tid];
}

// ---- kernel 2: gather pre-thresholded candidates + rank + full MLP ----
__global__ __launch_bounds__(1024, 1) void selmlp_kernel(
    const float* __restrict__ x, const int* __restrict__ cnts,
    const unsigned long long* __restrict__ cand,
    const float* __restrict__ w1, const float* __restrict__ W_ih,
    const float* __restrict__ b_ih, const float* __restrict__ b_hh,
    const float* __restrict__ w2, const float* __restrict__ W2,
    const float* __restrict__ b2, const float* __restrict__ w3,
    const float* __restrict__ W3, const float* __restrict__ b3,
    float* __restrict__ out) {
  __shared__ __align__(16) float hbuf[K1 * 65 + K2 * 65 + K2 * 33];  // 98.2 KB
  __shared__ __align__(16) unsigned long long comp[1024];   // 8 KB
  __shared__ __align__(16) unsigned long long sorted[512];  // 4 KB
  __shared__ __align__(16) float fa[4608];                  // 18 KB
  __shared__ int soff[SEGS + 1];
  __shared__ int wred[16];
  __shared__ int s_fb, s_ctot, s_lo, s_hi, s_done, s_cnt;
  __shared__ uint32_t s_T;
  __shared__ float s_inv[3];

  float* xsel = fa;                  // [K1*L1]
  float* sWih = fa + 1640;
  float* sbih = fa + 1960;           // b_ih + b_hh
  float* sW2  = fa + 2024;           // [L3][65]
  float* sb2  = fa + 4104;
  float* sw2v = fa + 4136;
  float* sw3v = fa + 4200;
  float* sW3  = fa + 4232;
  float* sb3  = fa + 4488;

  const int tid = threadIdx.x;
  const int wid = tid >> 6;
  const int g = blockIdx.x;
  const float* xg = x + (size_t)g * NPG * L1;

  // stage weights + norms
  for (int i = tid; i < L2 * L1; i += 1024) sWih[i] = W_ih[i];
  for (int i = tid; i < L2; i += 1024) { sbih[i] = b_ih[i] + b_hh[i]; sw2v[i] = w2[i]; }
  for (int i = tid; i < L3 * L2; i += 1024) sW2[(i >> 6) * 65 + (i & 63)] = W2[i];
  for (int i = tid; i < L3; i += 1024) { sb2[i] = b2[i]; sw3v[i] = w3[i]; }
  for (int i = tid; i < L4 * L3; i += 1024) sW3[i] = W3[i];
  for (int i = tid; i < L4; i += 1024) sb3[i] = b3[i];
  if (tid < 64) {
    float a = (tid < L1) ? w1[tid] : 0.f;
    float b = w2[tid];
    float c = (tid < L3) ? w3[tid] : 0.f;
    a *= a; b *= b; c *= c;
    for (int d = 1; d < 64; d <<= 1) {
      a += __shfl_xor(a, d); b += __shfl_xor(b, d); c += __shfl_xor(c, d);
    }
    if (tid == 0) {
      s_inv[0] = 1.f / sqrtf(a); s_inv[1] = 1.f / sqrtf(b); s_inv[2] = 1.f / sqrtf(c);
      s_cnt = 0; s_done = 0; s_lo = 0; s_hi = 0;
    }
  }
  if (tid < SEGS) soff[tid] = cnts[g * SEGS + tid];
  __syncthreads();
  if (tid == 0) {   // serial 16-element scan + exactness gate
    int off = 0, fb = 0;
    for (int s2 = 0; s2 < SEGS; ++s2) {
      int c = soff[s2];
      if (c > CAP) fb = 1;
      soff[s2] = off;
      off += c;
    }
    soff[SEGS] = off;
    if (off < K1 || off > 1024) fb = 1;   // prior missed (P~1e-13) -> exact fallback
    s_fb = fb; s_ctot = off;
  }
  __syncthreads();

  if (!s_fb) {
    // gather: wave w copies segment w's candidates (<=64, one wave-read)
    const int wl = tid & 63;
    if (wid < SEGS) {
      const int o = soff[wid], c = soff[wid + 1] - o;
      if (wl < c) comp[o + wl] = cand[((size_t)g * SEGS + wid) * CAP + wl];
    }
    const int ctot = s_ctot;
    const int nrk = (ctot + 7) & ~7;      // typ. ~424
    if (tid >= ctot && tid < nrk) comp[tid] = 0ULL;
    __syncthreads();
    if (tid < nrk) {   // unrolled broadcast counting-rank
      unsigned long long c = comp[tid];
      int r = 0;
      for (int i = 0; i < nrk; i += 8) {
        ulonglong2 v0 = *(const ulonglong2*)&comp[i];
        ulonglong2 v1 = *(const ulonglong2*)&comp[i + 2];
        ulonglong2 v2 = *(const ulonglong2*)&comp[i + 4];
        ulonglong2 v3 = *(const ulonglong2*)&comp[i + 6];
        r += (v0.x > c) + (v0.y > c) + (v1.x > c) + (v1.y > c) +
             (v2.x > c) + (v2.y > c) + (v3.x > c) + (v3.y > c);
      }
      if (r < K1) sorted[r] = c;
    }
    __syncthreads();
  } else {
    // exact fallback (never expected): binary search on mono32 with streamed
    // recompute, then collect + rank.
    const float w10 = w1[0], w11 = w1[1], w12 = w1[2], w13 = w1[3], w14 = w1[4];
    if (tid == 0) { s_lo = 0; s_hi = -1; s_done = 0; }  // s_hi=-1 == 2^32 as uint
    __syncthreads();
    for (int it = 0; it < 36; ++it) {
      if (s_done) break;
      const uint32_t lo = (uint32_t)s_lo, hi = (uint32_t)s_hi;
      const uint32_t q = (uint32_t)(((unsigned long long)lo + (unsigned long long)hi) >> 1);
      int cc = 0;
      for (int m = 0; m < 32; ++m) {
        const int i = m * 1024 + tid;
        const float* r = xg + (size_t)i * L1;
        float dv = r[0]*w10 + r[1]*w11 + r[2]*w12 + r[3]*w13 + r[4]*w14;
        cc += (mono(dv) >= q);
      }
      for (int d = 1; d < 64; d <<= 1) cc += __shfl_xor(cc, d);
      if ((tid & 63) == 0) wred[wid] = cc;
      __syncthreads();
      if (tid == 0) {
        int tot = 0;
        for (int w = 0; w < 16; ++w) tot += wred[w];
        if (tot >= K1 && tot <= 1024) { s_T = q; s_done = 1; }
        else if ((uint32_t)s_hi - (uint32_t)s_lo <= 1u) { s_T = (uint32_t)s_lo; s_done = 1; }
        else if (tot > 1024) { s_lo = (int)q; }
        else                 { s_hi = (int)q; }
      }
      __syncthreads();
    }
    const uint32_t T = s_T;
    for (int m = 0; m < 32; ++m) {
      const int i = m * 1024 + tid;
      const float* r = xg + (size_t)i * L1;
      float dv = r[0]*w10 + r[1]*w11 + r[2]*w12 + r[3]*w13 + r[4]*w14;
      if (mono(dv) >= T) {
        int p = atomicAdd(&s_cnt, 1);
        if (p < 1024)
          comp[p] = ((unsigned long long)mono(dv) << 16) | (unsigned)(65535 - i);
      }
    }
    __syncthreads();
    int cnt = s_cnt; if (cnt > 1024) cnt = 1024;
    int nrk = (cnt + 7) & ~7; if (nrk < 8) nrk = 8;
    if (tid >= cnt && tid < nrk) comp[tid] = 0ULL;
    __syncthreads();
    if (tid < nrk) {
      unsigned long long c = comp[tid];
      int r = 0;
      for (int i = 0; i < nrk; i += 8) {
        ulonglong2 v0 = *(const ulonglong2*)&comp[i];
        ulonglong2 v1 = *(const ulonglong2*)&comp[i + 2];
        ulonglong2 v2 = *(const ulonglong2*)&comp[i + 4];
        ulonglong2 v3 = *(const ulonglong2*)&comp[i + 6];
        r += (v0.x > c) + (v0.y > c) + (v1.x > c) + (v1.y > c) +
             (v2.x > c) + (v2.y > c) + (v3.x > c) + (v3.y > c);
      }
      if (r < K1) sorted[r] = c;
    }
    __syncthreads();
  }

  const float inv1 = s_inv[0], inv2 = s_inv[1], inv3 = s_inv[2];

  // phase E: gather x rows * score1
  for (int p = tid; p < K1 * L1; p += 1024) {
    int j = p / L1, k = p - j * L1;
    unsigned long long c = sorted[j];
    int idx = 65535 - (int)(c & 0xFFFFu);
    float sc = fast_tanh(imono((uint32_t)(c >> 16)) * inv1);
    xsel[p] = xg[(size_t)idx * L1 + k] * sc;
  }
  __syncthreads();
  // RNNCell -> h[328][65-stride]
  for (int p = tid; p < K1 * L2; p += 1024) {
    int row = p >> 6, o = p & 63;
    const float* wr = sWih + o * L1;
    const float* xr = xsel + row * L1;
    float acc = sbih[o];
#pragma unroll
    for (int k = 0; k < L1; ++k) acc += xr[k] * wr[k];
    hbuf[row * 65 + o] = fast_tanh(acc);
  }
  __syncthreads();

  // pool2: scores -> comp[0..384), counting-rank(384) -> sorted
  for (int j = tid; j < 384; j += 1024) {
    unsigned long long c = 0ULL;
    if (j < K1) {
      const float* hr = hbuf + j * 65;
      float acc = 0.f;
      for (int k = 0; k < L2; ++k) acc += hr[k] * sw2v[k];
      c = ((unsigned long long)mono(acc) << 16) | (unsigned)(65535 - j);
    }
    comp[j] = c;
  }
  __syncthreads();
  if (tid < 384) {
    unsigned long long c = comp[tid];
    int r = 0;
    for (int i = 0; i < 384; i += 8) {
      ulonglong2 v0 = *(const ulonglong2*)&comp[i];
      ulonglong2 v1 = *(const ulonglong2*)&comp[i + 2];
      ulonglong2 v2 = *(const ulonglong2*)&comp[i + 4];
      ulonglong2 v3 = *(const ulonglong2*)&comp[i + 6];
      r += (v0.x > c) + (v0.y > c) + (v1.x > c) + (v1.y > c) +
           (v2.x > c) + (v2.y > c) + (v3.x > c) + (v3.y > c);
    }
    sorted[r] = c;
  }
  __syncthreads();

  // phase G: x2[33][65-stride] = h[sel] * score2
  float* x2f = hbuf + K1 * 65;
  for (int p = tid; p < K2 * L2; p += 1024) {
    int j = p >> 6, k = p & 63;
    unsigned long long c = sorted[j];
    int row = 65535 - (int)(c & 0xFFFFu);
    float sc = fast_tanh(imono((uint32_t)(c >> 16)) * inv2);
    x2f[j * 65 + k] = hbuf[row * 65 + k] * sc;
  }
  __syncthreads();

  // phase H: y[33][32] = relu(x2 @ W2^T + b2)
  float* yf = x2f + K2 * 65;  // stride 33
  for (int p = tid; p < K2 * L3; p += 1024) {
    int j = p >> 5, o = p & 31;
    const float* xr = x2f + j * 65;
    const float* wr = sW2 + o * 65;
    float acc = sb2[o];
    for (int k = 0; k < L2; ++k) acc += xr[k] * wr[k];
    yf[j * 33 + o] = fmaxf(acc, 0.f);
  }
  __syncthreads();

  // pool3: scores -> comp[0..64), counting-rank(64) -> sorted
  for (int j = tid; j < 64; j += 1024) {
    unsigned long long c = 0ULL;
    if (j < K2) {
      const float* yr = yf + j * 33;
      float acc = 0.f;
      for (int k = 0; k < L3; ++k) acc += yr[k] * sw3v[k];
      c = ((unsigned long long)mono(acc) << 16) | (unsigned)(65535 - j);
    }
    comp[j] = c;
  }
  __syncthreads();
  if (tid < 64) {
    unsigned long long c = comp[tid];
    int r = 0;
    for (int i = 0; i < 64; i += 8) {
      ulonglong2 v0 = *(const ulonglong2*)&comp[i];
      ulonglong2 v1 = *(const ulonglong2*)&comp[i + 2];
      ulonglong2 v2 = *(const ulonglong2*)&comp[i + 4];
      ulonglong2 v3 = *(const ulonglong2*)&comp[i + 6];
      r += (v0.x > c) + (v0.y > c) + (v1.x > c) + (v1.y > c) +
           (v2.x > c) + (v2.y > c) + (v3.x > c) + (v3.y > c);
    }
    sorted[r] = c;
  }
  __syncthreads();

  // phase J: out[4][8] = (y[sel]*score3) @ W3^T + b3
  for (int p = tid; p < K3 * L4; p += 1024) {
    int t = p >> 3, o = p & 7;
    unsigned long long c = sorted[t];
    int row = 65535 - (int)(c & 0xFFFFu);
    float sc = fast_tanh(imono((uint32_t)(c >> 16)) * inv3);
    const float* yr = yf + row * 33;
    const float* wr = sW3 + o * L3;
    float acc = sb3[o];
    for (int k = 0; k < L3; ++k) acc += yr[k] * sc * wr[k];
    out[((size_t)g * K3 + t) * L4 + o] = acc;
  }
}

extern "C" void kernel_launch(void* const* d_in, const int* in_sizes, int n_in,
                              void* d_out, int out_size, void* d_ws, size_t ws_size,
                              hipStream_t stream) {
  const float* x    = (const float*)d_in[0];
  // d_in[1] = edge_index (unused), d_in[2] = batch (unused: static contiguous grouping)
  const float* w1   = (const float*)d_in[3];
  const float* W_ih = (const float*)d_in[4];
  const float* b_ih = (const float*)d_in[5];
  const float* b_hh = (const float*)d_in[6];
  const float* w2   = (const float*)d_in[7];
  const float* W2   = (const float*)d_in[8];
  const float* b2   = (const float*)d_in[9];
  const float* w3   = (const float*)d_in[10];
  const float* W3   = (const float*)d_in[11];
  const float* b3   = (const float*)d_in[12];
  float* out = (float*)d_out;

  int* cnts = (int*)d_ws;                                             // 8 KB
  unsigned long long* cand =
      (unsigned long long*)((char*)d_ws + 8192);                      // 1 MB

  score_kernel<<<dim3(NGRAPH * SEGS), dim3(256), 0, stream>>>(x, w1, cnts, cand);
  selmlp_kernel<<<dim3(NGRAPH), dim3(1024), 0, stream>>>(
      x, cnts, cand, w1, W_ih, b_ih, b_hh, w2, W2, b2, w3, W3, b3, out);
}